// Round 8
// baseline (233.506 us; speedup 1.0000x reference)
//
#include <hip/hip_runtime.h>
#include <hip/hip_fp16.h>

constexpr int IN_F = 128;
constexpr int NH   = 4;    // heads
constexpr int ND   = 32;   // dim per head
constexpr int HD   = 128;  // NH*ND
constexpr float NEG_SLOPE = 0.2f;

using short8 = __attribute__((ext_vector_type(8))) short;
using f32x4  = __attribute__((ext_vector_type(4))) float;

__device__ inline unsigned bf16b(float f) {  // f32 -> bf16 bits, RNE
  unsigned u = __float_as_uint(f);
  return (u + 0x7FFFu + ((u >> 16) & 1u)) >> 16;
}

// ---- Kernel P: one-shot build of swizzled bf16 W^T-extended tile ----------
// + grid-stride zero of deg (replaces hipMemsetAsync launch).
__global__ __launch_bounds__(256) void k_prep(
    const float* __restrict__ W, const float* __restrict__ attn_l,
    const float* __restrict__ attn_r, unsigned* __restrict__ wtx,
    int* __restrict__ deg, int n) {
  const int item = blockIdx.x * 256 + threadIdx.x;
  if (item < 144 * 16) {
    const int r = item >> 4, s = item & 15;
    const int k0 = s * 8;
    unsigned pk[4];
    if (r < HD) {
#pragma unroll
      for (int j2 = 0; j2 < 4; ++j2) {
        const unsigned lo = bf16b(W[(size_t)(k0 + 2 * j2) * HD + r]);
        const unsigned hi = bf16b(W[(size_t)(k0 + 2 * j2 + 1) * HD + r]);
        pk[j2] = lo | (hi << 16);
      }
    } else if (r < HD + 8) {
      const int j8 = r - HD;
      const int h = j8 & 3;
      const float* av = (j8 < 4 ? attn_l : attn_r) + h * ND;
      float sums[8];
#pragma unroll
      for (int j = 0; j < 8; ++j) {
        const float4* wv = (const float4*)&W[(size_t)(k0 + j) * HD + h * ND];
        const float4* a4 = (const float4*)av;
        float sum = 0.f;
#pragma unroll
        for (int c4 = 0; c4 < ND / 4; ++c4) {
          const float4 w = wv[c4], a = a4[c4];
          sum += w.x * a.x + w.y * a.y + w.z * a.z + w.w * a.w;
        }
        sums[j] = sum;
      }
#pragma unroll
      for (int j2 = 0; j2 < 4; ++j2)
        pk[j2] = bf16b(sums[2 * j2]) | (bf16b(sums[2 * j2 + 1]) << 16);
    } else {
      pk[0] = pk[1] = pk[2] = pk[3] = 0;
    }
    *(uint4*)&wtx[r * 64 + ((s ^ (r & 7)) << 2)] =
        make_uint4(pk[0], pk[1], pk[2], pk[3]);
  }
  for (int i = item; i < n; i += gridDim.x * 256) deg[i] = 0;
}

// ---- Kernel A: MFMA GEMM + fused rank/histogram tail ----------------------
__global__ __launch_bounds__(256) void k_gemm(
    const float* __restrict__ feat, const unsigned* __restrict__ wtx,
    unsigned* __restrict__ ftb2, float* __restrict__ el, float* __restrict__ er,
    const int* __restrict__ dst, int* __restrict__ deg, int* __restrict__ rank,
    int n, int ne) {
  __shared__ unsigned sB[144 * 64];  // 36864 B
  const int t = threadIdx.x;
  {  // coalesced 36 KB copy, layout already swizzled
    const uint4* wx = (const uint4*)wtx;
    uint4* sx = (uint4*)sB;
    for (int it = t; it < 144 * 16; it += 256) sx[it] = wx[it];
  }
  __syncthreads();

  const int lane = t & 63;
  const int wv   = t >> 6;
  const int r0   = blockIdx.x * 128 + wv * 32;
  const int lrow = lane & 15;
  const int lk   = lane >> 4;

  if (r0 < n) {
    f32x4 acc[2][9];
#pragma unroll
    for (int st = 0; st < 2; ++st)
#pragma unroll
      for (int ct = 0; ct < 9; ++ct) acc[st][ct] = (f32x4)0.f;

#pragma unroll
    for (int ks = 0; ks < 4; ++ks) {
      short8 b[9];
#pragma unroll
      for (int ct = 0; ct < 9; ++ct) {
        const int row = ct * 16 + lrow;
        const int slot = ks * 4 + lk;
        b[ct] = *(const short8*)&sB[row * 64 + ((slot ^ (row & 7)) << 2)];
      }
#pragma unroll
      for (int st = 0; st < 2; ++st) {
        int arow = r0 + st * 16 + lrow;
        arow = arow < n ? arow : n - 1;
        const float* ap = feat + (size_t)arow * IN_F + ks * 32 + lk * 8;
        const float4 f0 = *(const float4*)ap;
        const float4 f1 = *(const float4*)(ap + 4);
        short8 a;
        a[0] = (short)bf16b(f0.x); a[1] = (short)bf16b(f0.y);
        a[2] = (short)bf16b(f0.z); a[3] = (short)bf16b(f0.w);
        a[4] = (short)bf16b(f1.x); a[5] = (short)bf16b(f1.y);
        a[6] = (short)bf16b(f1.z); a[7] = (short)bf16b(f1.w);
#pragma unroll
        for (int ct = 0; ct < 9; ++ct)
          acc[st][ct] = __builtin_amdgcn_mfma_f32_16x16x32_bf16(a, b[ct], acc[st][ct], 0, 0, 0);
      }
    }

#pragma unroll
    for (int st = 0; st < 2; ++st) {
#pragma unroll
      for (int i = 0; i < 4; ++i) {
        const int r = r0 + st * 16 + lk * 4 + i;
        if (r >= n) continue;
#pragma unroll
        for (int ct = 0; ct < 4; ++ct) {
          const unsigned pk = bf16b(acc[st][ct][i]) | (bf16b(acc[st][ct + 4][i]) << 16);
          ftb2[(size_t)r * 64 + ct * 16 + lrow] = pk;
        }
        if (lrow < 4)      el[r * NH + lrow]     = acc[st][8][i];
        else if (lrow < 8) er[r * NH + lrow - 4] = acc[st][8][i];
      }
    }
  }

  // ---- fused rank/histogram: overlaps with other blocks' GEMM phase ----
  const int gstride = gridDim.x * 1024;  // 256 threads * 4 edges
  for (int e4 = (blockIdx.x * 256 + t) * 4; e4 < ne; e4 += gstride) {
    if (e4 + 4 <= ne) {
      const int4 d = *(const int4*)(dst + e4);
      int4 r;
      r.x = atomicAdd(deg + d.x, 1);
      r.y = atomicAdd(deg + d.y, 1);
      r.z = atomicAdd(deg + d.z, 1);
      r.w = atomicAdd(deg + d.w, 1);
      *(int4*)(rank + e4) = r;
    } else {
      for (int e = e4; e < ne; ++e) rank[e] = atomicAdd(deg + dst[e], 1);
    }
  }
}

// ---------------- Scan: per-block scan + fused finalize --------------------
__global__ __launch_bounds__(256) void k_scan1(
    const int* __restrict__ deg, int* __restrict__ pexcl,
    int* __restrict__ bsum, int n) {
  const int t = threadIdx.x;
  const int base = blockIdx.x * 1024 + t * 4;
  int v0 = base + 0 < n ? deg[base + 0] : 0;
  int v1 = base + 1 < n ? deg[base + 1] : 0;
  int v2 = base + 2 < n ? deg[base + 2] : 0;
  int v3 = base + 3 < n ? deg[base + 3] : 0;
  const int s = v0 + v1 + v2 + v3;
  const int lane = t & 63, w = t >> 6;
  int x = s;
#pragma unroll
  for (int off = 1; off < 64; off <<= 1) {
    int y = __shfl_up(x, off);
    if (lane >= off) x += y;
  }
  __shared__ int ws[4];
  if (lane == 63) ws[w] = x;
  __syncthreads();
  int woff = 0;
  for (int i = 0; i < w; ++i) woff += ws[i];
  int run = woff + x - s;
  if (base + 0 < n) { pexcl[base + 0] = run; run += v0; }
  if (base + 1 < n) { pexcl[base + 1] = run; run += v1; }
  if (base + 2 < n) { pexcl[base + 2] = run; run += v2; }
  if (base + 3 < n) { pexcl[base + 3] = run; run += v3; }
  if (t == 0) bsum[blockIdx.x] = ws[0] + ws[1] + ws[2] + ws[3];
}

// scan2+scan3 fused: each block re-scans bsum (B<=256, cheap) and finalizes
// its 1024-element slice of offsets.
__global__ __launch_bounds__(256) void k_scan23(
    const int* __restrict__ pexcl, const int* __restrict__ bsum,
    int* __restrict__ offsets, int B, int n, int ne) {
  const int t = threadIdx.x;
  const int s = t < B ? bsum[t] : 0;
  const int lane = t & 63, w = t >> 6;
  int x = s;
#pragma unroll
  for (int off = 1; off < 64; off <<= 1) {
    int y = __shfl_up(x, off);
    if (lane >= off) x += y;
  }
  __shared__ int ws[4];
  __shared__ int sboff[256];
  if (lane == 63) ws[w] = x;
  __syncthreads();
  int woff = 0;
  for (int i = 0; i < w; ++i) woff += ws[i];
  sboff[t] = woff + x - s;
  __syncthreads();
  const int myoff = sboff[blockIdx.x];
  const int base = blockIdx.x * 1024 + t * 4;
#pragma unroll
  for (int j = 0; j < 4; ++j)
    if (base + j < n) offsets[base + j] = pexcl[base + j] + myoff;
  if (blockIdx.x == 0 && t == 0) offsets[n] = ne;
}

// ---- Kernel S: scatter combined record, 2 edges/thread --------------------
// rec[pos] = { src, half2(p0,p2), half2(p1,p3), 0 } : ONE 16B write per edge.
__global__ __launch_bounds__(256) void k_scatter(
    const int* __restrict__ src, const int* __restrict__ dst,
    const int* __restrict__ rank, const int* __restrict__ offsets,
    const float* __restrict__ el, const float* __restrict__ er,
    int4* __restrict__ rec, int ne) {
  const int e0 = (blockIdx.x * 256 + threadIdx.x) * 2;
  if (e0 >= ne) return;

#define MAKEREC(S, D, K)                                              \
  {                                                                   \
    const int pos = offsets[D] + (K);                                 \
    const float4 l = *(const float4*)(el + (size_t)(S) * NH);         \
    const float4 r = *(const float4*)(er + (size_t)(D) * NH);         \
    float e0_ = l.x + r.x, e1_ = l.y + r.y, e2_ = l.z + r.z, e3_ = l.w + r.w; \
    e0_ = e0_ > 0.f ? e0_ : NEG_SLOPE * e0_;                          \
    e1_ = e1_ > 0.f ? e1_ : NEG_SLOPE * e1_;                          \
    e2_ = e2_ > 0.f ? e2_ : NEG_SLOPE * e2_;                          \
    e3_ = e3_ > 0.f ? e3_ : NEG_SLOPE * e3_;                          \
    const __half2 h02 = __float22half2_rn(make_float2(__expf(e0_), __expf(e2_))); \
    const __half2 h13 = __float22half2_rn(make_float2(__expf(e1_), __expf(e3_))); \
    int4 rc;                                                          \
    rc.x = (S);                                                       \
    rc.y = *(const int*)&h02;                                         \
    rc.z = *(const int*)&h13;                                         \
    rc.w = 0;                                                         \
    rec[pos] = rc;                                                    \
  }

  if (e0 + 2 <= ne) {
    const int2 s2 = *(const int2*)(src + e0);
    const int2 d2 = *(const int2*)(dst + e0);
    const int2 k2 = *(const int2*)(rank + e0);
    MAKEREC(s2.x, d2.x, k2.x)
    MAKEREC(s2.y, d2.y, k2.y)
  } else {
    MAKEREC(src[e0], dst[e0], rank[e0])
  }
#undef MAKEREC
}

// ------ Kernel D: aggregation, one wave per dst node, 8-deep pipeline ------
__global__ __launch_bounds__(256) void k_aggr(
    const int* __restrict__ offsets, const int4* __restrict__ rec,
    const unsigned* __restrict__ ftb2, float* __restrict__ out, int n) {
  const int wid = (blockIdx.x * 256 + threadIdx.x) >> 6;
  if (wid >= n) return;
  const int lane = threadIdx.x & 63;
  const int hsel = lane >> 5;  // elem 'lane' -> head hsel; elem lane+64 -> 2+hsel
  const int start = offsets[wid], end = offsets[wid + 1];
  float acc0 = 0.f, acc1 = 0.f, den0 = 0.f, den1 = 0.f;

#define EDGE(R)                                                   \
  {                                                               \
    const int pw = hsel ? (R).z : (R).y;                          \
    const __half2 hp = *(const __half2*)&pw;                      \
    const float2 pf = __half22float2(hp);                         \
    const unsigned v = ftb2[(size_t)(R).x * 64 + lane];           \
    acc0 += __uint_as_float(v << 16) * pf.x;                      \
    acc1 += __uint_as_float(v & 0xFFFF0000u) * pf.y;              \
    den0 += pf.x;                                                 \
    den1 += pf.y;                                                 \
  }

  int i = start;
  for (; i + 8 <= end; i += 8) {
    const int4 r0 = rec[i + 0];   // 8 independent broadcast loads,
    const int4 r1 = rec[i + 1];   // then 8 independent gathers
    const int4 r2 = rec[i + 2];
    const int4 r3 = rec[i + 3];
    const int4 r4 = rec[i + 4];
    const int4 r5 = rec[i + 5];
    const int4 r6 = rec[i + 6];
    const int4 r7 = rec[i + 7];
    EDGE(r0) EDGE(r1) EDGE(r2) EDGE(r3) EDGE(r4) EDGE(r5) EDGE(r6) EDGE(r7)
  }
  for (; i < end; ++i) {
    const int4 rr = rec[i];
    EDGE(rr)
  }
#undef EDGE

  den0 = den0 > 0.f ? den0 : 1.f;  // isolated-node guard (matches reference)
  den1 = den1 > 0.f ? den1 : 1.f;
  float* orow = out + (size_t)wid * HD;
  orow[lane] = acc0 / den0;
  orow[64 + lane] = acc1 / den1;
}

extern "C" void kernel_launch(void* const* d_in, const int* in_sizes, int n_in,
                              void* d_out, int out_size, void* d_ws, size_t ws_size,
                              hipStream_t stream) {
  const float* feat   = (const float*)d_in[0];
  const float* W      = (const float*)d_in[1];
  const float* attn_l = (const float*)d_in[2];
  const float* attn_r = (const float*)d_in[3];
  const int*   src    = (const int*)d_in[4];
  const int*   dst    = (const int*)d_in[5];
  const int n  = in_sizes[0] / IN_F;
  const int ne = in_sizes[4];
  float* out = (float*)d_out;

  // workspace layout (16B-aligned blocks first)
  char* wp = (char*)d_ws;
  unsigned* ftb2    = (unsigned*)wp; wp += (size_t)n * 64 * 4;    // 25.6 MB
  int4*  rec        = (int4*)wp;     wp += (size_t)ne * 16;       // 25.6 MB
  unsigned* wtx     = (unsigned*)wp; wp += (size_t)144 * 64 * 4;  // 36 KB
  float* el         = (float*)wp;    wp += (size_t)n * NH * 4;
  float* er         = (float*)wp;    wp += (size_t)n * NH * 4;
  int*   rank       = (int*)wp;      wp += (size_t)ne * 4;
  int*   deg        = (int*)wp;      wp += (size_t)n * 4;
  int*   pexcl      = (int*)wp;      wp += (size_t)n * 4;
  int*   offsets    = (int*)wp;      wp += (size_t)(n + 1) * 4;
  int*   bsum       = (int*)wp;      wp += 256 * 4;

  const int B = (n + 1023) / 1024;
  k_prep<<<64, 256, 0, stream>>>(W, attn_l, attn_r, wtx, deg, n);
  k_gemm<<<(n + 127) / 128, 256, 0, stream>>>(feat, wtx, ftb2, el, er,
                                              dst, deg, rank, n, ne);
  k_scan1<<<B, 256, 0, stream>>>(deg, pexcl, bsum, n);
  k_scan23<<<B, 256, 0, stream>>>(pexcl, bsum, offsets, B, n, ne);
  k_scatter<<<(ne / 2 + 255) / 256, 256, 0, stream>>>(src, dst, rank, offsets,
                                                      el, er, rec, ne);
  k_aggr<<<(n + 3) / 4, 256, 0, stream>>>(offsets, rec, ftb2, out, n);
}

// Round 9
// 176.900 us; speedup vs baseline: 1.3200x; 1.3200x over previous
//
#include <hip/hip_runtime.h>
#include <hip/hip_fp16.h>

constexpr int IN_F = 128;
constexpr int NH   = 4;    // heads
constexpr int ND   = 32;   // dim per head
constexpr int HD   = 128;  // NH*ND
constexpr float NEG_SLOPE = 0.2f;
constexpr int NBLK   = 256;  // partition chunk count (table minor dim)
constexpr int BSH    = 7;    // 128 nodes per coarse bucket
constexpr int BNODES = 1 << BSH;

using short8 = __attribute__((ext_vector_type(8))) short;
using f32x4  = __attribute__((ext_vector_type(4))) float;

__device__ inline unsigned bf16b(float f) {  // f32 -> bf16 bits, RNE
  unsigned u = __float_as_uint(f);
  return (u + 0x7FFFu + ((u >> 16) & 1u)) >> 16;
}

// ---- Kernel P: one-shot build of swizzled bf16 W^T-extended tile ----------
__global__ __launch_bounds__(256) void k_prep(
    const float* __restrict__ W, const float* __restrict__ attn_l,
    const float* __restrict__ attn_r, unsigned* __restrict__ wtx) {
  const int item = blockIdx.x * 256 + threadIdx.x;
  if (item >= 144 * 16) return;
  const int r = item >> 4, s = item & 15;
  const int k0 = s * 8;
  unsigned pk[4];
  if (r < HD) {
#pragma unroll
    for (int j2 = 0; j2 < 4; ++j2) {
      const unsigned lo = bf16b(W[(size_t)(k0 + 2 * j2) * HD + r]);
      const unsigned hi = bf16b(W[(size_t)(k0 + 2 * j2 + 1) * HD + r]);
      pk[j2] = lo | (hi << 16);
    }
  } else if (r < HD + 8) {
    const int j8 = r - HD;
    const int h = j8 & 3;
    const float* av = (j8 < 4 ? attn_l : attn_r) + h * ND;
    float sums[8];
#pragma unroll
    for (int j = 0; j < 8; ++j) {
      const float4* wv = (const float4*)&W[(size_t)(k0 + j) * HD + h * ND];
      const float4* a4 = (const float4*)av;
      float sum = 0.f;
#pragma unroll
      for (int c4 = 0; c4 < ND / 4; ++c4) {
        const float4 w = wv[c4], a = a4[c4];
        sum += w.x * a.x + w.y * a.y + w.z * a.z + w.w * a.w;
      }
      sums[j] = sum;
    }
#pragma unroll
    for (int j2 = 0; j2 < 4; ++j2)
      pk[j2] = bf16b(sums[2 * j2]) | (bf16b(sums[2 * j2 + 1]) << 16);
  } else {
    pk[0] = pk[1] = pk[2] = pk[3] = 0;
  }
  *(uint4*)&wtx[r * 64 + ((s ^ (r & 7)) << 2)] = make_uint4(pk[0], pk[1], pk[2], pk[3]);
}

// ---- Kernel A: MFMA GEMM  ft(bf16-pair-packed) + el/er fused as extra cols -
__global__ __launch_bounds__(256) void k_gemm(
    const float* __restrict__ feat, const unsigned* __restrict__ wtx,
    unsigned* __restrict__ ftb2, float* __restrict__ el, float* __restrict__ er,
    int n) {
  __shared__ unsigned sB[144 * 64];  // 36864 B
  const int t = threadIdx.x;
  {
    const uint4* wx = (const uint4*)wtx;
    uint4* sx = (uint4*)sB;
    for (int it = t; it < 144 * 16; it += 256) sx[it] = wx[it];
  }
  __syncthreads();

  const int lane = t & 63;
  const int wv   = t >> 6;
  const int r0   = blockIdx.x * 128 + wv * 32;
  if (r0 >= n) return;
  const int lrow = lane & 15;
  const int lk   = lane >> 4;

  f32x4 acc[2][9];
#pragma unroll
  for (int st = 0; st < 2; ++st)
#pragma unroll
    for (int ct = 0; ct < 9; ++ct) acc[st][ct] = (f32x4)0.f;

#pragma unroll
  for (int ks = 0; ks < 4; ++ks) {
    short8 b[9];
#pragma unroll
    for (int ct = 0; ct < 9; ++ct) {
      const int row = ct * 16 + lrow;
      const int slot = ks * 4 + lk;
      b[ct] = *(const short8*)&sB[row * 64 + ((slot ^ (row & 7)) << 2)];
    }
#pragma unroll
    for (int st = 0; st < 2; ++st) {
      int arow = r0 + st * 16 + lrow;
      arow = arow < n ? arow : n - 1;
      const float* ap = feat + (size_t)arow * IN_F + ks * 32 + lk * 8;
      const float4 f0 = *(const float4*)ap;
      const float4 f1 = *(const float4*)(ap + 4);
      short8 a;
      a[0] = (short)bf16b(f0.x); a[1] = (short)bf16b(f0.y);
      a[2] = (short)bf16b(f0.z); a[3] = (short)bf16b(f0.w);
      a[4] = (short)bf16b(f1.x); a[5] = (short)bf16b(f1.y);
      a[6] = (short)bf16b(f1.z); a[7] = (short)bf16b(f1.w);
#pragma unroll
      for (int ct = 0; ct < 9; ++ct)
        acc[st][ct] = __builtin_amdgcn_mfma_f32_16x16x32_bf16(a, b[ct], acc[st][ct], 0, 0, 0);
    }
  }

#pragma unroll
  for (int st = 0; st < 2; ++st) {
#pragma unroll
    for (int i = 0; i < 4; ++i) {
      const int r = r0 + st * 16 + lk * 4 + i;
      if (r >= n) continue;
#pragma unroll
      for (int ct = 0; ct < 4; ++ct) {
        const unsigned pk = bf16b(acc[st][ct][i]) | (bf16b(acc[st][ct + 4][i]) << 16);
        ftb2[(size_t)r * 64 + ct * 16 + lrow] = pk;
      }
      if (lrow < 4)      el[r * NH + lrow]     = acc[st][8][i];
      else if (lrow < 8) er[r * NH + lrow - 4] = acc[st][8][i];
    }
  }
}

// ---- Kernel H: per-chunk coarse histogram (LDS atomics only) --------------
// cnt[bucket][chunk] ; bucket = dst >> BSH (<=1024 buckets supported)
__global__ __launch_bounds__(256) void k_chist(
    const int* __restrict__ dst, int* __restrict__ cnt, int ne, int nbuk) {
  __shared__ int hist[1024];
  const int t = threadIdx.x;
  for (int b = t; b < nbuk; b += 256) hist[b] = 0;
  __syncthreads();
  const int chunk = (ne + NBLK - 1) / NBLK;
  const int start = blockIdx.x * chunk;
  const int end = min(start + chunk, ne);
  for (int e = start + t; e < end; e += 256)
    atomicAdd(&hist[dst[e] >> BSH], 1);
  __syncthreads();
  for (int b = t; b < nbuk; b += 256) cnt[b * NBLK + blockIdx.x] = hist[b];
}

// ---------------- Scan over the cnt table (generic length) -----------------
__global__ __launch_bounds__(256) void k_scan1(
    const int* __restrict__ in, int* __restrict__ pexcl,
    int* __restrict__ bsum, int len) {
  const int t = threadIdx.x;
  const int base = blockIdx.x * 1024 + t * 4;
  int v0 = base + 0 < len ? in[base + 0] : 0;
  int v1 = base + 1 < len ? in[base + 1] : 0;
  int v2 = base + 2 < len ? in[base + 2] : 0;
  int v3 = base + 3 < len ? in[base + 3] : 0;
  const int s = v0 + v1 + v2 + v3;
  const int lane = t & 63, w = t >> 6;
  int x = s;
#pragma unroll
  for (int off = 1; off < 64; off <<= 1) {
    int y = __shfl_up(x, off);
    if (lane >= off) x += y;
  }
  __shared__ int ws[4];
  if (lane == 63) ws[w] = x;
  __syncthreads();
  int woff = 0;
  for (int i = 0; i < w; ++i) woff += ws[i];
  int run = woff + x - s;
  if (base + 0 < len) { pexcl[base + 0] = run; run += v0; }
  if (base + 1 < len) { pexcl[base + 1] = run; run += v1; }
  if (base + 2 < len) { pexcl[base + 2] = run; run += v2; }
  if (base + 3 < len) { pexcl[base + 3] = run; run += v3; }
  if (t == 0) bsum[blockIdx.x] = ws[0] + ws[1] + ws[2] + ws[3];
}

__global__ __launch_bounds__(256) void k_scan23(
    const int* __restrict__ pexcl, const int* __restrict__ bsum,
    int* __restrict__ outv, int B, int len) {
  const int t = threadIdx.x;
  const int s = t < B ? bsum[t] : 0;
  const int lane = t & 63, w = t >> 6;
  int x = s;
#pragma unroll
  for (int off = 1; off < 64; off <<= 1) {
    int y = __shfl_up(x, off);
    if (lane >= off) x += y;
  }
  __shared__ int ws[4];
  __shared__ int sboff[256];
  if (lane == 63) ws[w] = x;
  __syncthreads();
  int woff = 0;
  for (int i = 0; i < w; ++i) woff += ws[i];
  sboff[t] = woff + x - s;
  __syncthreads();
  const int myoff = sboff[blockIdx.x];
  const int base = blockIdx.x * 1024 + t * 4;
#pragma unroll
  for (int j = 0; j < 4; ++j)
    if (base + j < len) outv[base + j] = pexcl[base + j] + myoff;
}

// ---- Kernel B: partition (src,dst) into coarse-bucket order ---------------
__global__ __launch_bounds__(256) void k_part(
    const int* __restrict__ src, const int* __restrict__ dst,
    const int* __restrict__ scanned, int2* __restrict__ pair, int ne, int nbuk) {
  __shared__ int cur[1024];
  const int t = threadIdx.x;
  for (int b = t; b < nbuk; b += 256) cur[b] = scanned[b * NBLK + blockIdx.x];
  __syncthreads();
  const int chunk = (ne + NBLK - 1) / NBLK;
  const int start = blockIdx.x * chunk;
  const int end = min(start + chunk, ne);
  for (int e = start + t; e < end; e += 256) {
    const int d = dst[e];
    const int pos = atomicAdd(&cur[d >> BSH], 1);
    pair[pos] = make_int2(src[e], d);
  }
}

// ---- Kernel C: per-bucket fine counting sort + rec build + offsets --------
__global__ __launch_bounds__(256) void k_fsort(
    const int2* __restrict__ pair, const int* __restrict__ scanned,
    const float* __restrict__ el, const float* __restrict__ er,
    int* __restrict__ offsets, int4* __restrict__ rec,
    int n, int ne, int nbuk) {
  const int b = blockIdx.x;
  const int t = threadIdx.x;
  const int base = scanned[b * NBLK];
  const int endp = (b + 1 < nbuk) ? scanned[(b + 1) * NBLK] : ne;
  __shared__ int hist[BNODES];
  __shared__ int cur[BNODES];
  __shared__ int ws2[2];
  if (t < BNODES) hist[t] = 0;
  __syncthreads();
  for (int i = base + t; i < endp; i += 256)
    atomicAdd(&hist[pair[i].y & (BNODES - 1)], 1);
  __syncthreads();
  int x = 0, v = 0;
  if (t < BNODES) {  // 2 full waves: wave-local inclusive scan
    v = hist[t];
    x = v;
    const int lane = t & 63;
#pragma unroll
    for (int off = 1; off < 64; off <<= 1) {
      int y = __shfl_up(x, off);
      if (lane >= off) x += y;
    }
    if (lane == 63) ws2[t >> 6] = x;
  }
  __syncthreads();
  if (t < BNODES) {
    if (t >= 64) x += ws2[0];
    const int excl = base + x - v;  // global exclusive offset for node
    cur[t] = excl;
    const int node = (b << BSH) + t;
    if (node < n) offsets[node] = excl;
  }
  if (b == 0 && t == 0) offsets[n] = ne;
  __syncthreads();
  for (int i = base + t; i < endp; i += 256) {
    const int2 pr = pair[i];
    const int pos = atomicAdd(&cur[pr.y & (BNODES - 1)], 1);
    const float4 l = *(const float4*)(el + (size_t)pr.x * NH);
    const float4 r = *(const float4*)(er + (size_t)pr.y * NH);
    float e0 = l.x + r.x, e1 = l.y + r.y, e2 = l.z + r.z, e3 = l.w + r.w;
    e0 = e0 > 0.f ? e0 : NEG_SLOPE * e0;
    e1 = e1 > 0.f ? e1 : NEG_SLOPE * e1;
    e2 = e2 > 0.f ? e2 : NEG_SLOPE * e2;
    e3 = e3 > 0.f ? e3 : NEG_SLOPE * e3;
    // |logits| <= ~8: exp() safe without segment-max; softmax ratio identical
    const __half2 h02 = __float22half2_rn(make_float2(__expf(e0), __expf(e2)));
    const __half2 h13 = __float22half2_rn(make_float2(__expf(e1), __expf(e3)));
    int4 rc;
    rc.x = pr.x;
    rc.y = *(const int*)&h02;
    rc.z = *(const int*)&h13;
    rc.w = 0;
    rec[pos] = rc;
  }
}

// ------ Kernel D: aggregation, one wave per dst node, 8-deep pipeline ------
__global__ __launch_bounds__(256) void k_aggr(
    const int* __restrict__ offsets, const int4* __restrict__ rec,
    const unsigned* __restrict__ ftb2, float* __restrict__ out, int n) {
  const int wid = (blockIdx.x * 256 + threadIdx.x) >> 6;
  if (wid >= n) return;
  const int lane = threadIdx.x & 63;
  const int hsel = lane >> 5;
  const int start = offsets[wid], end = offsets[wid + 1];
  float acc0 = 0.f, acc1 = 0.f, den0 = 0.f, den1 = 0.f;

#define EDGE(R)                                                   \
  {                                                               \
    const int pw = hsel ? (R).z : (R).y;                          \
    const __half2 hp = *(const __half2*)&pw;                      \
    const float2 pf = __half22float2(hp);                         \
    const unsigned v = ftb2[(size_t)(R).x * 64 + lane];           \
    acc0 += __uint_as_float(v << 16) * pf.x;                      \
    acc1 += __uint_as_float(v & 0xFFFF0000u) * pf.y;              \
    den0 += pf.x;                                                 \
    den1 += pf.y;                                                 \
  }

  int i = start;
  for (; i + 8 <= end; i += 8) {
    const int4 r0 = rec[i + 0];
    const int4 r1 = rec[i + 1];
    const int4 r2 = rec[i + 2];
    const int4 r3 = rec[i + 3];
    const int4 r4 = rec[i + 4];
    const int4 r5 = rec[i + 5];
    const int4 r6 = rec[i + 6];
    const int4 r7 = rec[i + 7];
    EDGE(r0) EDGE(r1) EDGE(r2) EDGE(r3) EDGE(r4) EDGE(r5) EDGE(r6) EDGE(r7)
  }
  for (; i < end; ++i) {
    const int4 rr = rec[i];
    EDGE(rr)
  }
#undef EDGE

  den0 = den0 > 0.f ? den0 : 1.f;  // isolated-node guard (matches reference)
  den1 = den1 > 0.f ? den1 : 1.f;
  float* orow = out + (size_t)wid * HD;
  orow[lane] = acc0 / den0;
  orow[64 + lane] = acc1 / den1;
}

extern "C" void kernel_launch(void* const* d_in, const int* in_sizes, int n_in,
                              void* d_out, int out_size, void* d_ws, size_t ws_size,
                              hipStream_t stream) {
  const float* feat   = (const float*)d_in[0];
  const float* W      = (const float*)d_in[1];
  const float* attn_l = (const float*)d_in[2];
  const float* attn_r = (const float*)d_in[3];
  const int*   src    = (const int*)d_in[4];
  const int*   dst    = (const int*)d_in[5];
  const int n  = in_sizes[0] / IN_F;
  const int ne = in_sizes[4];
  float* out = (float*)d_out;

  const int nbuk = (n + BNODES - 1) >> BSH;   // coarse buckets (<=1024)
  const int tbl  = nbuk * NBLK;               // cnt table length
  const int Bt   = (tbl + 1023) / 1024;       // scan blocks (<=256)

  // workspace layout (16B-aligned blocks first)
  char* wp = (char*)d_ws;
  unsigned* ftb2 = (unsigned*)wp; wp += (size_t)n * 64 * 4;    // 25.6 MB
  int4*  rec     = (int4*)wp;     wp += (size_t)ne * 16;       // 25.6 MB
  int2*  pair    = (int2*)wp;     wp += (size_t)ne * 8;        // 12.8 MB
  unsigned* wtx  = (unsigned*)wp; wp += (size_t)144 * 64 * 4;  // 36 KB
  float* el      = (float*)wp;    wp += (size_t)n * NH * 4;
  float* er      = (float*)wp;    wp += (size_t)n * NH * 4;
  int*   cnt     = (int*)wp;      wp += (size_t)tbl * 4;
  int*   pexcl   = (int*)wp;      wp += (size_t)tbl * 4;
  int*   scanned = (int*)wp;      wp += (size_t)tbl * 4;
  int*   offsets = (int*)wp;      wp += (size_t)(n + 1) * 4;
  int*   bsum    = (int*)wp;      wp += 256 * 4;

  k_prep<<<9, 256, 0, stream>>>(W, attn_l, attn_r, wtx);
  k_gemm<<<(n + 127) / 128, 256, 0, stream>>>(feat, wtx, ftb2, el, er, n);
  k_chist<<<NBLK, 256, 0, stream>>>(dst, cnt, ne, nbuk);
  k_scan1<<<Bt, 256, 0, stream>>>(cnt, pexcl, bsum, tbl);
  k_scan23<<<Bt, 256, 0, stream>>>(pexcl, bsum, scanned, Bt, tbl);
  k_part<<<NBLK, 256, 0, stream>>>(src, dst, scanned, pair, ne, nbuk);
  k_fsort<<<nbuk, 256, 0, stream>>>(pair, scanned, el, er, offsets, rec, n, ne, nbuk);
  k_aggr<<<(n + 3) / 4, 256, 0, stream>>>(offsets, rec, ftb2, out, n);
}

// Round 10
// 156.108 us; speedup vs baseline: 1.4958x; 1.1332x over previous
//
#include <hip/hip_runtime.h>
#include <hip/hip_fp16.h>

constexpr int IN_F = 128;
constexpr int NH   = 4;    // heads
constexpr int ND   = 32;   // dim per head
constexpr int HD   = 128;  // NH*ND
constexpr float NEG_SLOPE = 0.2f;
constexpr int NBLK   = 256;  // partition chunk count (table minor dim)
constexpr int BSH    = 7;    // 128 nodes per coarse bucket
constexpr int BNODES = 1 << BSH;

using short8 = __attribute__((ext_vector_type(8))) short;
using f32x4  = __attribute__((ext_vector_type(4))) float;
using f32x2  = __attribute__((ext_vector_type(2))) float;

__device__ inline unsigned bf16b(float f) {  // f32 -> bf16 bits, RNE
  unsigned u = __float_as_uint(f);
  return (u + 0x7FFFu + ((u >> 16) & 1u)) >> 16;
}

// ---- Kernel H: coarse histogram (LDS atomics) + fused wtx prep ------------
// cnt[bucket][chunk]; bucket = dst >> BSH. Blocks 0..8 also build the
// swizzled bf16 W^T-extended tile (2304 items).
__global__ __launch_bounds__(256) void k_chist(
    const int* __restrict__ dst, int* __restrict__ cnt, int ne, int nbuk,
    const float* __restrict__ W, const float* __restrict__ attn_l,
    const float* __restrict__ attn_r, unsigned* __restrict__ wtx) {
  const int t = threadIdx.x;
  const int item = blockIdx.x * 256 + t;
  if (item < 144 * 16) {  // ---- prep part ----
    const int r = item >> 4, s = item & 15;
    const int k0 = s * 8;
    unsigned pk[4];
    if (r < HD) {
#pragma unroll
      for (int j2 = 0; j2 < 4; ++j2) {
        const unsigned lo = bf16b(W[(size_t)(k0 + 2 * j2) * HD + r]);
        const unsigned hi = bf16b(W[(size_t)(k0 + 2 * j2 + 1) * HD + r]);
        pk[j2] = lo | (hi << 16);
      }
    } else if (r < HD + 8) {
      const int j8 = r - HD;
      const int h = j8 & 3;
      const float* av = (j8 < 4 ? attn_l : attn_r) + h * ND;
      float sums[8];
#pragma unroll
      for (int j = 0; j < 8; ++j) {
        const float4* wv = (const float4*)&W[(size_t)(k0 + j) * HD + h * ND];
        const float4* a4 = (const float4*)av;
        float sum = 0.f;
#pragma unroll
        for (int c4 = 0; c4 < ND / 4; ++c4) {
          const float4 w = wv[c4], a = a4[c4];
          sum += w.x * a.x + w.y * a.y + w.z * a.z + w.w * a.w;
        }
        sums[j] = sum;
      }
#pragma unroll
      for (int j2 = 0; j2 < 4; ++j2)
        pk[j2] = bf16b(sums[2 * j2]) | (bf16b(sums[2 * j2 + 1]) << 16);
    } else {
      pk[0] = pk[1] = pk[2] = pk[3] = 0;
    }
    *(uint4*)&wtx[r * 64 + ((s ^ (r & 7)) << 2)] =
        make_uint4(pk[0], pk[1], pk[2], pk[3]);
  }
  // ---- histogram part ----
  __shared__ int hist[1024];
  for (int b = t; b < nbuk; b += 256) hist[b] = 0;
  __syncthreads();
  const int chunk = (ne + NBLK - 1) / NBLK;
  const int start = blockIdx.x * chunk;
  const int end = min(start + chunk, ne);
  for (int e = start + t; e < end; e += 256)
    atomicAdd(&hist[dst[e] >> BSH], 1);
  __syncthreads();
  for (int b = t; b < nbuk; b += 256) cnt[b * NBLK + blockIdx.x] = hist[b];
}

// ---- Kernel A: MFMA GEMM  ft(bf16-pair-packed) + el/er fused as extra cols -
__global__ __launch_bounds__(256) void k_gemm(
    const float* __restrict__ feat, const unsigned* __restrict__ wtx,
    unsigned* __restrict__ ftb2, float* __restrict__ el, float* __restrict__ er,
    int n) {
  __shared__ unsigned sB[144 * 64];  // 36864 B
  const int t = threadIdx.x;
  {
    const uint4* wx = (const uint4*)wtx;
    uint4* sx = (uint4*)sB;
    for (int it = t; it < 144 * 16; it += 256) sx[it] = wx[it];
  }
  __syncthreads();

  const int lane = t & 63;
  const int wv   = t >> 6;
  const int r0   = blockIdx.x * 128 + wv * 32;
  if (r0 >= n) return;
  const int lrow = lane & 15;
  const int lk   = lane >> 4;

  f32x4 acc[2][9];
#pragma unroll
  for (int st = 0; st < 2; ++st)
#pragma unroll
    for (int ct = 0; ct < 9; ++ct) acc[st][ct] = (f32x4)0.f;

#pragma unroll
  for (int ks = 0; ks < 4; ++ks) {
    short8 b[9];
#pragma unroll
    for (int ct = 0; ct < 9; ++ct) {
      const int row = ct * 16 + lrow;
      const int slot = ks * 4 + lk;
      b[ct] = *(const short8*)&sB[row * 64 + ((slot ^ (row & 7)) << 2)];
    }
#pragma unroll
    for (int st = 0; st < 2; ++st) {
      int arow = r0 + st * 16 + lrow;
      arow = arow < n ? arow : n - 1;
      const float* ap = feat + (size_t)arow * IN_F + ks * 32 + lk * 8;
      const float4 f0 = *(const float4*)ap;
      const float4 f1 = *(const float4*)(ap + 4);
      short8 a;
      a[0] = (short)bf16b(f0.x); a[1] = (short)bf16b(f0.y);
      a[2] = (short)bf16b(f0.z); a[3] = (short)bf16b(f0.w);
      a[4] = (short)bf16b(f1.x); a[5] = (short)bf16b(f1.y);
      a[6] = (short)bf16b(f1.z); a[7] = (short)bf16b(f1.w);
#pragma unroll
      for (int ct = 0; ct < 9; ++ct)
        acc[st][ct] = __builtin_amdgcn_mfma_f32_16x16x32_bf16(a, b[ct], acc[st][ct], 0, 0, 0);
    }
  }

#pragma unroll
  for (int st = 0; st < 2; ++st) {
#pragma unroll
    for (int i = 0; i < 4; ++i) {
      const int r = r0 + st * 16 + lk * 4 + i;
      if (r >= n) continue;
#pragma unroll
      for (int ct = 0; ct < 4; ++ct) {
        const unsigned pk = bf16b(acc[st][ct][i]) | (bf16b(acc[st][ct + 4][i]) << 16);
        ftb2[(size_t)r * 64 + ct * 16 + lrow] = pk;
      }
      if (lrow < 4)      el[r * NH + lrow]     = acc[st][8][i];
      else if (lrow < 8) er[r * NH + lrow - 4] = acc[st][8][i];
    }
  }
}

// ---------------- Scan over the cnt table (generic length) -----------------
__global__ __launch_bounds__(256) void k_scan1(
    const int* __restrict__ in, int* __restrict__ pexcl,
    int* __restrict__ bsum, int len) {
  const int t = threadIdx.x;
  const int base = blockIdx.x * 1024 + t * 4;
  int v0 = base + 0 < len ? in[base + 0] : 0;
  int v1 = base + 1 < len ? in[base + 1] : 0;
  int v2 = base + 2 < len ? in[base + 2] : 0;
  int v3 = base + 3 < len ? in[base + 3] : 0;
  const int s = v0 + v1 + v2 + v3;
  const int lane = t & 63, w = t >> 6;
  int x = s;
#pragma unroll
  for (int off = 1; off < 64; off <<= 1) {
    int y = __shfl_up(x, off);
    if (lane >= off) x += y;
  }
  __shared__ int ws[4];
  if (lane == 63) ws[w] = x;
  __syncthreads();
  int woff = 0;
  for (int i = 0; i < w; ++i) woff += ws[i];
  int run = woff + x - s;
  if (base + 0 < len) { pexcl[base + 0] = run; run += v0; }
  if (base + 1 < len) { pexcl[base + 1] = run; run += v1; }
  if (base + 2 < len) { pexcl[base + 2] = run; run += v2; }
  if (base + 3 < len) { pexcl[base + 3] = run; run += v3; }
  if (t == 0) bsum[blockIdx.x] = ws[0] + ws[1] + ws[2] + ws[3];
}

__global__ __launch_bounds__(256) void k_scan23(
    const int* __restrict__ pexcl, const int* __restrict__ bsum,
    int* __restrict__ outv, int B, int len) {
  const int t = threadIdx.x;
  const int s = t < B ? bsum[t] : 0;
  const int lane = t & 63, w = t >> 6;
  int x = s;
#pragma unroll
  for (int off = 1; off < 64; off <<= 1) {
    int y = __shfl_up(x, off);
    if (lane >= off) x += y;
  }
  __shared__ int ws[4];
  __shared__ int sboff[256];
  if (lane == 63) ws[w] = x;
  __syncthreads();
  int woff = 0;
  for (int i = 0; i < w; ++i) woff += ws[i];
  sboff[t] = woff + x - s;
  __syncthreads();
  const int myoff = sboff[blockIdx.x];
  const int base = blockIdx.x * 1024 + t * 4;
#pragma unroll
  for (int j = 0; j < 4; ++j)
    if (base + j < len) outv[base + j] = pexcl[base + j] + myoff;
}

// ---- Kernel B: partition (src,dst) into coarse-bucket order ---------------
__global__ __launch_bounds__(256) void k_part(
    const int* __restrict__ src, const int* __restrict__ dst,
    const int* __restrict__ scanned, int2* __restrict__ pair, int ne, int nbuk) {
  __shared__ int cur[1024];
  const int t = threadIdx.x;
  for (int b = t; b < nbuk; b += 256) cur[b] = scanned[b * NBLK + blockIdx.x];
  __syncthreads();
  const int chunk = (ne + NBLK - 1) / NBLK;
  const int start = blockIdx.x * chunk;
  const int end = min(start + chunk, ne);
  for (int e = start + t; e < end; e += 256) {
    const int d = dst[e];
    const int pos = atomicAdd(&cur[d >> BSH], 1);
    pair[pos] = make_int2(src[e], d);
  }
}

// ---- Kernel C: per-bucket fine counting sort + rec build + offsets --------
// rec[pos] = { src, h02, src, h13 }  (src duplicated for 8B lane loads)
__global__ __launch_bounds__(256) void k_fsort(
    const int2* __restrict__ pair, const int* __restrict__ scanned,
    const float* __restrict__ el, const float* __restrict__ er,
    int* __restrict__ offsets, int4* __restrict__ rec,
    int n, int ne, int nbuk) {
  const int b = blockIdx.x;
  const int t = threadIdx.x;
  const int base = scanned[b * NBLK];
  const int endp = (b + 1 < nbuk) ? scanned[(b + 1) * NBLK] : ne;
  __shared__ int hist[BNODES];
  __shared__ int cur[BNODES];
  __shared__ int ws2[2];
  if (t < BNODES) hist[t] = 0;
  __syncthreads();
  for (int i = base + t; i < endp; i += 256)
    atomicAdd(&hist[pair[i].y & (BNODES - 1)], 1);
  __syncthreads();
  int x = 0, v = 0;
  if (t < BNODES) {
    v = hist[t];
    x = v;
    const int lane = t & 63;
#pragma unroll
    for (int off = 1; off < 64; off <<= 1) {
      int y = __shfl_up(x, off);
      if (lane >= off) x += y;
    }
    if (lane == 63) ws2[t >> 6] = x;
  }
  __syncthreads();
  if (t < BNODES) {
    if (t >= 64) x += ws2[0];
    const int excl = base + x - v;
    cur[t] = excl;
    const int node = (b << BSH) + t;
    if (node < n) offsets[node] = excl;
  }
  if (b == 0 && t == 0) offsets[n] = ne;
  __syncthreads();
  for (int i = base + t; i < endp; i += 256) {
    const int2 pr = pair[i];
    const int pos = atomicAdd(&cur[pr.y & (BNODES - 1)], 1);
    const float4 l = *(const float4*)(el + (size_t)pr.x * NH);
    const float4 r = *(const float4*)(er + (size_t)pr.y * NH);
    float e0 = l.x + r.x, e1 = l.y + r.y, e2 = l.z + r.z, e3 = l.w + r.w;
    e0 = e0 > 0.f ? e0 : NEG_SLOPE * e0;
    e1 = e1 > 0.f ? e1 : NEG_SLOPE * e1;
    e2 = e2 > 0.f ? e2 : NEG_SLOPE * e2;
    e3 = e3 > 0.f ? e3 : NEG_SLOPE * e3;
    // |logits| <= ~8: exp() safe without segment-max; softmax ratio identical
    const __half2 h02 = __float22half2_rn(make_float2(__expf(e0), __expf(e2)));
    const __half2 h13 = __float22half2_rn(make_float2(__expf(e1), __expf(e3)));
    int4 rc;
    rc.x = pr.x;
    rc.y = *(const int*)&h02;
    rc.z = pr.x;
    rc.w = *(const int*)&h13;
    rec[pos] = rc;
  }
}

// ------ Kernel D: aggregation, 16 lanes per node, 4 nodes per wave ---------
// Lane c (0..15) gathers uint4 = ftb2 cols 4c..4c+3: elems 4c..4c+3 (head
// c<8?0:1, weight p.x) and 4c+64.. (head +2, weight p.y). rec 8B lane load.
__global__ __launch_bounds__(256) void k_aggr(
    const int* __restrict__ offsets, const int* __restrict__ rec,
    const unsigned* __restrict__ ftb2, float* __restrict__ out, int n) {
  const int t = threadIdx.x;
  const int lane = t & 63;
  const int gw = (blockIdx.x * 256 + t) >> 6;  // global wave id
  const int q = lane >> 4;                     // quarter 0..3
  const int c = lane & 15;                     // lane within quarter
  const int hsel = c >> 3;                     // 0:(p0,p2) 1:(p1,p3)
  const int node = gw * 4 + q;
  int start = 0, end = 0;
  if (node < n) { start = offsets[node]; end = offsets[node + 1]; }
  int md = end - start;
  md = max(md, __shfl_xor(md, 16));
  md = max(md, __shfl_xor(md, 32));            // wave-max degree
  const char* recb = (const char*)rec + (hsel << 3);
  const unsigned* fb = ftb2 + (c << 2);

  f32x2 acc0 = {0.f, 0.f}, acc1 = {0.f, 0.f};
  f32x2 acc2 = {0.f, 0.f}, acc3 = {0.f, 0.f};
  f32x2 den  = {0.f, 0.f};

  for (int it = 0; it < md; it += 4) {
    int2 r[4];
#pragma unroll
    for (int k = 0; k < 4; ++k) {
      const int idx = start + it + k;
      int cl = min(idx, end - 1);
      cl = cl < 0 ? 0 : cl;
      r[k] = *(const int2*)(recb + ((size_t)cl << 4));
      if (idx >= end) r[k].y = 0;  // p = 0 for padded slots
    }
#pragma unroll
    for (int k = 0; k < 4; ++k) {
      const uint4 v = *(const uint4*)(fb + (size_t)r[k].x * 64);
      const float2 pf = __half22float2(*(const __half2*)&r[k].y);
      f32x2 p; p.x = pf.x; p.y = pf.y;
      f32x2 f;
      f.x = __uint_as_float(v.x << 16);
      f.y = __uint_as_float(v.x & 0xFFFF0000u);
      asm("v_pk_fma_f32 %0, %1, %2, %0" : "+v"(acc0) : "v"(f), "v"(p));
      f.x = __uint_as_float(v.y << 16);
      f.y = __uint_as_float(v.y & 0xFFFF0000u);
      asm("v_pk_fma_f32 %0, %1, %2, %0" : "+v"(acc1) : "v"(f), "v"(p));
      f.x = __uint_as_float(v.z << 16);
      f.y = __uint_as_float(v.z & 0xFFFF0000u);
      asm("v_pk_fma_f32 %0, %1, %2, %0" : "+v"(acc2) : "v"(f), "v"(p));
      f.x = __uint_as_float(v.w << 16);
      f.y = __uint_as_float(v.w & 0xFFFF0000u);
      asm("v_pk_fma_f32 %0, %1, %2, %0" : "+v"(acc3) : "v"(f), "v"(p));
      asm("v_pk_add_f32 %0, %1, %0" : "+v"(den) : "v"(p));
    }
  }

  if (node < n) {
    const float d0 = den.x > 0.f ? den.x : 1.f;  // isolated-node guard
    const float d1 = den.y > 0.f ? den.y : 1.f;
    const float r0 = __builtin_amdgcn_rcpf(d0);  // ~1ulp, within budget
    const float r1 = __builtin_amdgcn_rcpf(d1);
    float* orow = out + (size_t)node * HD;
    *(float4*)(orow + (c << 2)) =
        make_float4(acc0.x * r0, acc1.x * r0, acc2.x * r0, acc3.x * r0);
    *(float4*)(orow + 64 + (c << 2)) =
        make_float4(acc0.y * r1, acc1.y * r1, acc2.y * r1, acc3.y * r1);
  }
}

extern "C" void kernel_launch(void* const* d_in, const int* in_sizes, int n_in,
                              void* d_out, int out_size, void* d_ws, size_t ws_size,
                              hipStream_t stream) {
  const float* feat   = (const float*)d_in[0];
  const float* W      = (const float*)d_in[1];
  const float* attn_l = (const float*)d_in[2];
  const float* attn_r = (const float*)d_in[3];
  const int*   src    = (const int*)d_in[4];
  const int*   dst    = (const int*)d_in[5];
  const int n  = in_sizes[0] / IN_F;
  const int ne = in_sizes[4];
  float* out = (float*)d_out;

  const int nbuk = (n + BNODES - 1) >> BSH;   // coarse buckets (<=1024)
  const int tbl  = nbuk * NBLK;               // cnt table length
  const int Bt   = (tbl + 1023) / 1024;       // scan blocks (<=256)

  // workspace layout (16B-aligned blocks first)
  char* wp = (char*)d_ws;
  unsigned* ftb2 = (unsigned*)wp; wp += (size_t)n * 64 * 4;    // 25.6 MB
  int4*  rec     = (int4*)wp;     wp += (size_t)ne * 16;       // 25.6 MB
  int2*  pair    = (int2*)wp;     wp += (size_t)ne * 8;        // 12.8 MB
  unsigned* wtx  = (unsigned*)wp; wp += (size_t)144 * 64 * 4;  // 36 KB
  float* el      = (float*)wp;    wp += (size_t)n * NH * 4;
  float* er      = (float*)wp;    wp += (size_t)n * NH * 4;
  int*   cnt     = (int*)wp;      wp += (size_t)tbl * 4;
  int*   pexcl   = (int*)wp;      wp += (size_t)tbl * 4;
  int*   scanned = (int*)wp;      wp += (size_t)tbl * 4;
  int*   offsets = (int*)wp;      wp += (size_t)(n + 1) * 4;
  int*   bsum    = (int*)wp;      wp += 256 * 4;

  k_chist<<<NBLK, 256, 0, stream>>>(dst, cnt, ne, nbuk, W, attn_l, attn_r, wtx);
  k_gemm<<<(n + 127) / 128, 256, 0, stream>>>(feat, wtx, ftb2, el, er, n);
  k_scan1<<<Bt, 256, 0, stream>>>(cnt, pexcl, bsum, tbl);
  k_scan23<<<Bt, 256, 0, stream>>>(pexcl, bsum, scanned, Bt, tbl);
  k_part<<<NBLK, 256, 0, stream>>>(src, dst, scanned, pair, ne, nbuk);
  k_fsort<<<nbuk, 256, 0, stream>>>(pair, scanned, el, er, offsets, rec, n, ne, nbuk);
  k_aggr<<<(n + 15) / 16, 256, 0, stream>>>(offsets, (const int*)rec, ftb2, out, n);
}

// Round 11
// 144.404 us; speedup vs baseline: 1.6170x; 1.0810x over previous
//
#include <hip/hip_runtime.h>
#include <hip/hip_fp16.h>

constexpr int IN_F = 128;
constexpr int NH   = 4;    // heads
constexpr int ND   = 32;   // dim per head
constexpr int HD   = 128;  // NH*ND
constexpr float NEG_SLOPE = 0.2f;
constexpr int NBLK   = 256;  // partition chunk count (table minor dim)
constexpr int BSH    = 7;    // 128 nodes per coarse bucket
constexpr int BNODES = 1 << BSH;

using short8 = __attribute__((ext_vector_type(8))) short;
using f32x4  = __attribute__((ext_vector_type(4))) float;
using f32x2  = __attribute__((ext_vector_type(2))) float;

__device__ inline unsigned bf16b(float f) {  // f32 -> bf16 bits, RNE
  unsigned u = __float_as_uint(f);
  return (u + 0x7FFFu + ((u >> 16) & 1u)) >> 16;
}

// ---- Kernel H: coarse histogram (LDS atomics) + fused wtx prep ------------
__global__ __launch_bounds__(256) void k_chist(
    const int* __restrict__ dst, int* __restrict__ cnt, int ne, int nbuk,
    const float* __restrict__ W, const float* __restrict__ attn_l,
    const float* __restrict__ attn_r, unsigned* __restrict__ wtx) {
  const int t = threadIdx.x;
  const int item = blockIdx.x * 256 + t;
  if (item < 144 * 16) {  // ---- prep part ----
    const int r = item >> 4, s = item & 15;
    const int k0 = s * 8;
    unsigned pk[4];
    if (r < HD) {
#pragma unroll
      for (int j2 = 0; j2 < 4; ++j2) {
        const unsigned lo = bf16b(W[(size_t)(k0 + 2 * j2) * HD + r]);
        const unsigned hi = bf16b(W[(size_t)(k0 + 2 * j2 + 1) * HD + r]);
        pk[j2] = lo | (hi << 16);
      }
    } else if (r < HD + 8) {
      const int j8 = r - HD;
      const int h = j8 & 3;
      const float* av = (j8 < 4 ? attn_l : attn_r) + h * ND;
      float sums[8];
#pragma unroll
      for (int j = 0; j < 8; ++j) {
        const float4* wv = (const float4*)&W[(size_t)(k0 + j) * HD + h * ND];
        const float4* a4 = (const float4*)av;
        float sum = 0.f;
#pragma unroll
        for (int c4 = 0; c4 < ND / 4; ++c4) {
          const float4 w = wv[c4], a = a4[c4];
          sum += w.x * a.x + w.y * a.y + w.z * a.z + w.w * a.w;
        }
        sums[j] = sum;
      }
#pragma unroll
      for (int j2 = 0; j2 < 4; ++j2)
        pk[j2] = bf16b(sums[2 * j2]) | (bf16b(sums[2 * j2 + 1]) << 16);
    } else {
      pk[0] = pk[1] = pk[2] = pk[3] = 0;
    }
    *(uint4*)&wtx[r * 64 + ((s ^ (r & 7)) << 2)] =
        make_uint4(pk[0], pk[1], pk[2], pk[3]);
  }
  __shared__ int hist[1024];
  for (int b = t; b < nbuk; b += 256) hist[b] = 0;
  __syncthreads();
  const int chunk = (ne + NBLK - 1) / NBLK;
  const int start = blockIdx.x * chunk;
  const int end = min(start + chunk, ne);
  for (int e = start + t; e < end; e += 256)
    atomicAdd(&hist[dst[e] >> BSH], 1);
  __syncthreads();
  for (int b = t; b < nbuk; b += 256) cnt[b * NBLK + blockIdx.x] = hist[b];
}

// ---------------- Scan over the cnt table (generic length) -----------------
__global__ __launch_bounds__(256) void k_scan1(
    const int* __restrict__ in, int* __restrict__ pexcl,
    int* __restrict__ bsum, int len) {
  const int t = threadIdx.x;
  const int base = blockIdx.x * 1024 + t * 4;
  int v0 = base + 0 < len ? in[base + 0] : 0;
  int v1 = base + 1 < len ? in[base + 1] : 0;
  int v2 = base + 2 < len ? in[base + 2] : 0;
  int v3 = base + 3 < len ? in[base + 3] : 0;
  const int s = v0 + v1 + v2 + v3;
  const int lane = t & 63, w = t >> 6;
  int x = s;
#pragma unroll
  for (int off = 1; off < 64; off <<= 1) {
    int y = __shfl_up(x, off);
    if (lane >= off) x += y;
  }
  __shared__ int ws[4];
  if (lane == 63) ws[w] = x;
  __syncthreads();
  int woff = 0;
  for (int i = 0; i < w; ++i) woff += ws[i];
  int run = woff + x - s;
  if (base + 0 < len) { pexcl[base + 0] = run; run += v0; }
  if (base + 1 < len) { pexcl[base + 1] = run; run += v1; }
  if (base + 2 < len) { pexcl[base + 2] = run; run += v2; }
  if (base + 3 < len) { pexcl[base + 3] = run; run += v3; }
  if (t == 0) bsum[blockIdx.x] = ws[0] + ws[1] + ws[2] + ws[3];
}

__global__ __launch_bounds__(256) void k_scan23(
    const int* __restrict__ pexcl, const int* __restrict__ bsum,
    int* __restrict__ outv, int B, int len) {
  const int t = threadIdx.x;
  const int s = t < B ? bsum[t] : 0;
  const int lane = t & 63, w = t >> 6;
  int x = s;
#pragma unroll
  for (int off = 1; off < 64; off <<= 1) {
    int y = __shfl_up(x, off);
    if (lane >= off) x += y;
  }
  __shared__ int ws[4];
  __shared__ int sboff[256];
  if (lane == 63) ws[w] = x;
  __syncthreads();
  int woff = 0;
  for (int i = 0; i < w; ++i) woff += ws[i];
  sboff[t] = woff + x - s;
  __syncthreads();
  const int myoff = sboff[blockIdx.x];
  const int base = blockIdx.x * 1024 + t * 4;
#pragma unroll
  for (int j = 0; j < 4; ++j)
    if (base + j < len) outv[base + j] = pexcl[base + j] + myoff;
}

// ---- Kernel A: MFMA GEMM + fused coarse-partition tail --------------------
// Blocks 0..NBLK-1 additionally scatter their edge chunk into coarse-bucket
// order as packed (src<<BSH)|(dst&127) — overlaps other blocks' GEMM phase.
__global__ __launch_bounds__(256) void k_gemm(
    const float* __restrict__ feat, const unsigned* __restrict__ wtx,
    unsigned* __restrict__ ftb2, float* __restrict__ el, float* __restrict__ er,
    int n, const int* __restrict__ src, const int* __restrict__ dst,
    const int* __restrict__ scanned, unsigned* __restrict__ pairp,
    int ne, int nbuk) {
  __shared__ unsigned sB[144 * 64];  // 36864 B
  __shared__ int cur[1024];          // 4 KB (part tail)
  const int t = threadIdx.x;
  {
    const uint4* wx = (const uint4*)wtx;
    uint4* sx = (uint4*)sB;
    for (int it = t; it < 144 * 16; it += 256) sx[it] = wx[it];
  }
  __syncthreads();

  const int lane = t & 63;
  const int wv   = t >> 6;
  const int r0   = blockIdx.x * 128 + wv * 32;
  const int lrow = lane & 15;
  const int lk   = lane >> 4;

  if (r0 < n) {
    f32x4 acc[2][9];
#pragma unroll
    for (int st = 0; st < 2; ++st)
#pragma unroll
      for (int ct = 0; ct < 9; ++ct) acc[st][ct] = (f32x4)0.f;

#pragma unroll
    for (int ks = 0; ks < 4; ++ks) {
      short8 b[9];
#pragma unroll
      for (int ct = 0; ct < 9; ++ct) {
        const int row = ct * 16 + lrow;
        const int slot = ks * 4 + lk;
        b[ct] = *(const short8*)&sB[row * 64 + ((slot ^ (row & 7)) << 2)];
      }
#pragma unroll
      for (int st = 0; st < 2; ++st) {
        int arow = r0 + st * 16 + lrow;
        arow = arow < n ? arow : n - 1;
        const float* ap = feat + (size_t)arow * IN_F + ks * 32 + lk * 8;
        const float4 f0 = *(const float4*)ap;
        const float4 f1 = *(const float4*)(ap + 4);
        short8 a;
        a[0] = (short)bf16b(f0.x); a[1] = (short)bf16b(f0.y);
        a[2] = (short)bf16b(f0.z); a[3] = (short)bf16b(f0.w);
        a[4] = (short)bf16b(f1.x); a[5] = (short)bf16b(f1.y);
        a[6] = (short)bf16b(f1.z); a[7] = (short)bf16b(f1.w);
#pragma unroll
        for (int ct = 0; ct < 9; ++ct)
          acc[st][ct] = __builtin_amdgcn_mfma_f32_16x16x32_bf16(a, b[ct], acc[st][ct], 0, 0, 0);
      }
    }

#pragma unroll
    for (int st = 0; st < 2; ++st) {
#pragma unroll
      for (int i = 0; i < 4; ++i) {
        const int r = r0 + st * 16 + lk * 4 + i;
        if (r >= n) continue;
#pragma unroll
        for (int ct = 0; ct < 4; ++ct) {
          const unsigned pk = bf16b(acc[st][ct][i]) | (bf16b(acc[st][ct + 4][i]) << 16);
          ftb2[(size_t)r * 64 + ct * 16 + lrow] = pk;
        }
        if (lrow < 4)      el[r * NH + lrow]     = acc[st][8][i];
        else if (lrow < 8) er[r * NH + lrow - 4] = acc[st][8][i];
      }
    }
  }

  // ---- coarse-partition tail (blocks 0..NBLK-1 only; all waves alive) ----
  if (blockIdx.x < NBLK) {
    for (int b = t; b < nbuk; b += 256) cur[b] = scanned[b * NBLK + blockIdx.x];
    __syncthreads();
    const int chunk = (ne + NBLK - 1) / NBLK;
    const int start = blockIdx.x * chunk;
    const int end = min(start + chunk, ne);
    for (int e = start + t; e < end; e += 256) {
      const int d = dst[e];
      const int pos = atomicAdd(&cur[d >> BSH], 1);
      pairp[pos] = ((unsigned)src[e] << BSH) | (unsigned)(d & (BNODES - 1));
    }
  }
}

// ---- Kernel C: per-bucket fine counting sort + rec build + offsets --------
// rec[pos] = { src, h02, src, h13 }  (src duplicated for 8B lane loads)
__global__ __launch_bounds__(256) void k_fsort(
    const unsigned* __restrict__ pair, const int* __restrict__ scanned,
    const float* __restrict__ el, const float* __restrict__ er,
    int* __restrict__ offsets, int4* __restrict__ rec,
    int n, int ne, int nbuk) {
  const int b = blockIdx.x;
  const int t = threadIdx.x;
  const int base = scanned[b * NBLK];
  const int endp = (b + 1 < nbuk) ? scanned[(b + 1) * NBLK] : ne;
  __shared__ int hist[BNODES];
  __shared__ int cur[BNODES];
  __shared__ int ws2[2];
  if (t < BNODES) hist[t] = 0;
  __syncthreads();
  for (int i = base + t; i < endp; i += 256)
    atomicAdd(&hist[pair[i] & (BNODES - 1)], 1);
  __syncthreads();
  int x = 0, v = 0;
  if (t < BNODES) {
    v = hist[t];
    x = v;
    const int lane = t & 63;
#pragma unroll
    for (int off = 1; off < 64; off <<= 1) {
      int y = __shfl_up(x, off);
      if (lane >= off) x += y;
    }
    if (lane == 63) ws2[t >> 6] = x;
  }
  __syncthreads();
  if (t < BNODES) {
    if (t >= 64) x += ws2[0];
    const int excl = base + x - v;
    cur[t] = excl;
    const int node = (b << BSH) + t;
    if (node < n) offsets[node] = excl;
  }
  if (b == 0 && t == 0) offsets[n] = ne;
  __syncthreads();
  for (int i = base + t; i < endp; i += 256) {
    const unsigned pr = pair[i];
    const int s = (int)(pr >> BSH);
    const int fn = (int)(pr & (BNODES - 1));
    const int d = (b << BSH) + fn;
    const int pos = atomicAdd(&cur[fn], 1);
    const float4 l = *(const float4*)(el + (size_t)s * NH);
    const float4 r = *(const float4*)(er + (size_t)d * NH);
    float e0 = l.x + r.x, e1 = l.y + r.y, e2 = l.z + r.z, e3 = l.w + r.w;
    e0 = e0 > 0.f ? e0 : NEG_SLOPE * e0;
    e1 = e1 > 0.f ? e1 : NEG_SLOPE * e1;
    e2 = e2 > 0.f ? e2 : NEG_SLOPE * e2;
    e3 = e3 > 0.f ? e3 : NEG_SLOPE * e3;
    // |logits| <= ~8: exp() safe without segment-max; softmax ratio identical
    const __half2 h02 = __float22half2_rn(make_float2(__expf(e0), __expf(e2)));
    const __half2 h13 = __float22half2_rn(make_float2(__expf(e1), __expf(e3)));
    int4 rc;
    rc.x = s;
    rc.y = *(const int*)&h02;
    rc.z = s;
    rc.w = *(const int*)&h13;
    rec[pos] = rc;
  }
}

// ------ Kernel D: aggregation, 16 lanes/node, per-quarter loop bounds ------
// Finished quarters mask off via exec — no wasted wave-max fetches.
__global__ __launch_bounds__(256) void k_aggr(
    const int* __restrict__ offsets, const int* __restrict__ rec,
    const unsigned* __restrict__ ftb2, float* __restrict__ out, int n) {
  const int t = threadIdx.x;
  const int lane = t & 63;
  const int gw = (blockIdx.x * 256 + t) >> 6;  // global wave id
  const int q = lane >> 4;                     // quarter 0..3
  const int c = lane & 15;                     // lane within quarter
  const int hsel = c >> 3;                     // 0:(p0,p2) 1:(p1,p3)
  const int node = gw * 4 + q;
  int start = 0, end = 0;
  if (node < n) { start = offsets[node]; end = offsets[node + 1]; }
  const char* recb = (const char*)rec + (hsel << 3);
  const unsigned* fb = ftb2 + (c << 2);

  f32x2 acc0 = {0.f, 0.f}, acc1 = {0.f, 0.f};
  f32x2 acc2 = {0.f, 0.f}, acc3 = {0.f, 0.f};
  f32x2 den  = {0.f, 0.f};

  for (int i = start; i < end; i += 4) {  // divergent across quarters: OK
    int2 r[4];
#pragma unroll
    for (int k = 0; k < 4; ++k) {
      const int idx = i + k;
      const int cl = min(idx, end - 1);
      r[k] = *(const int2*)(recb + ((size_t)cl << 4));
      if (idx >= end) r[k].y = 0;  // p = 0 for intra-step padding
    }
#pragma unroll
    for (int k = 0; k < 4; ++k) {
      const uint4 v = *(const uint4*)(fb + (size_t)r[k].x * 64);
      const float2 pf = __half22float2(*(const __half2*)&r[k].y);
      f32x2 p; p.x = pf.x; p.y = pf.y;
      f32x2 f;
      f.x = __uint_as_float(v.x << 16);
      f.y = __uint_as_float(v.x & 0xFFFF0000u);
      asm("v_pk_fma_f32 %0, %1, %2, %0" : "+v"(acc0) : "v"(f), "v"(p));
      f.x = __uint_as_float(v.y << 16);
      f.y = __uint_as_float(v.y & 0xFFFF0000u);
      asm("v_pk_fma_f32 %0, %1, %2, %0" : "+v"(acc1) : "v"(f), "v"(p));
      f.x = __uint_as_float(v.z << 16);
      f.y = __uint_as_float(v.z & 0xFFFF0000u);
      asm("v_pk_fma_f32 %0, %1, %2, %0" : "+v"(acc2) : "v"(f), "v"(p));
      f.x = __uint_as_float(v.w << 16);
      f.y = __uint_as_float(v.w & 0xFFFF0000u);
      asm("v_pk_fma_f32 %0, %1, %2, %0" : "+v"(acc3) : "v"(f), "v"(p));
      asm("v_pk_add_f32 %0, %1, %0" : "+v"(den) : "v"(p));
    }
  }

  if (node < n) {
    const float d0 = den.x > 0.f ? den.x : 1.f;  // isolated-node guard
    const float d1 = den.y > 0.f ? den.y : 1.f;
    const float r0 = __builtin_amdgcn_rcpf(d0);
    const float r1 = __builtin_amdgcn_rcpf(d1);
    float* orow = out + (size_t)node * HD;
    *(float4*)(orow + (c << 2)) =
        make_float4(acc0.x * r0, acc1.x * r0, acc2.x * r0, acc3.x * r0);
    *(float4*)(orow + 64 + (c << 2)) =
        make_float4(acc0.y * r1, acc1.y * r1, acc2.y * r1, acc3.y * r1);
  }
}

extern "C" void kernel_launch(void* const* d_in, const int* in_sizes, int n_in,
                              void* d_out, int out_size, void* d_ws, size_t ws_size,
                              hipStream_t stream) {
  const float* feat   = (const float*)d_in[0];
  const float* W      = (const float*)d_in[1];
  const float* attn_l = (const float*)d_in[2];
  const float* attn_r = (const float*)d_in[3];
  const int*   src    = (const int*)d_in[4];
  const int*   dst    = (const int*)d_in[5];
  const int n  = in_sizes[0] / IN_F;
  const int ne = in_sizes[4];
  float* out = (float*)d_out;

  const int nbuk = (n + BNODES - 1) >> BSH;   // coarse buckets (<=1024)
  const int tbl  = nbuk * NBLK;               // cnt table length
  const int Bt   = (tbl + 1023) / 1024;       // scan blocks (<=256)

  // workspace layout (16B-aligned blocks first)
  char* wp = (char*)d_ws;
  unsigned* ftb2 = (unsigned*)wp; wp += (size_t)n * 64 * 4;    // 25.6 MB
  int4*  rec     = (int4*)wp;     wp += (size_t)ne * 16;       // 25.6 MB
  unsigned* pairp = (unsigned*)wp; wp += (size_t)ne * 4;       // 6.4 MB
  unsigned* wtx  = (unsigned*)wp; wp += (size_t)144 * 64 * 4;  // 36 KB
  float* el      = (float*)wp;    wp += (size_t)n * NH * 4;
  float* er      = (float*)wp;    wp += (size_t)n * NH * 4;
  int*   cnt     = (int*)wp;      wp += (size_t)tbl * 4;
  int*   pexcl   = (int*)wp;      wp += (size_t)tbl * 4;
  int*   scanned = (int*)wp;      wp += (size_t)tbl * 4;
  int*   offsets = (int*)wp;      wp += (size_t)(n + 1) * 4;
  int*   bsum    = (int*)wp;      wp += 256 * 4;

  k_chist<<<NBLK, 256, 0, stream>>>(dst, cnt, ne, nbuk, W, attn_l, attn_r, wtx);
  k_scan1<<<Bt, 256, 0, stream>>>(cnt, pexcl, bsum, tbl);
  k_scan23<<<Bt, 256, 0, stream>>>(pexcl, bsum, scanned, Bt, tbl);
  k_gemm<<<(n + 127) / 128, 256, 0, stream>>>(feat, wtx, ftb2, el, er, n,
                                              src, dst, scanned, pairp, ne, nbuk);
  k_fsort<<<nbuk, 256, 0, stream>>>(pairp, scanned, el, er, offsets, rec, n, ne, nbuk);
  k_aggr<<<(n + 15) / 16, 256, 0, stream>>>(offsets, (const int*)rec, ftb2, out, n);
}

// Round 12
// 133.506 us; speedup vs baseline: 1.7490x; 1.0816x over previous
//
#include <hip/hip_runtime.h>
#include <hip/hip_fp16.h>

constexpr int IN_F = 128;
constexpr int NH   = 4;    // heads
constexpr int ND   = 32;   // dim per head
constexpr int HD   = 128;  // NH*ND
constexpr float NEG_SLOPE = 0.2f;
constexpr int NBLK   = 256;  // partition chunk count (table minor dim)
constexpr int BSH    = 7;    // 128 nodes per coarse bucket
constexpr int BNODES = 1 << BSH;
constexpr int CAP    = 2560; // LDS record capacity per bucket (mean 2048, 11 sigma)

using short8 = __attribute__((ext_vector_type(8))) short;
using f32x4  = __attribute__((ext_vector_type(4))) float;
using f32x2  = __attribute__((ext_vector_type(2))) float;

__device__ inline unsigned bf16b(float f) {  // f32 -> bf16 bits, RNE
  unsigned u = __float_as_uint(f);
  return (u + 0x7FFFu + ((u >> 16) & 1u)) >> 16;
}

// ---- Kernel H: coarse histogram (LDS atomics) + fused wtx prep ------------
__global__ __launch_bounds__(256) void k_chist(
    const int* __restrict__ dst, int* __restrict__ cnt, int ne, int nbuk,
    const float* __restrict__ W, const float* __restrict__ attn_l,
    const float* __restrict__ attn_r, unsigned* __restrict__ wtx) {
  const int t = threadIdx.x;
  const int item = blockIdx.x * 256 + t;
  if (item < 144 * 16) {  // ---- prep part ----
    const int r = item >> 4, s = item & 15;
    const int k0 = s * 8;
    unsigned pk[4];
    if (r < HD) {
#pragma unroll
      for (int j2 = 0; j2 < 4; ++j2) {
        const unsigned lo = bf16b(W[(size_t)(k0 + 2 * j2) * HD + r]);
        const unsigned hi = bf16b(W[(size_t)(k0 + 2 * j2 + 1) * HD + r]);
        pk[j2] = lo | (hi << 16);
      }
    } else if (r < HD + 8) {
      const int j8 = r - HD;
      const int h = j8 & 3;
      const float* av = (j8 < 4 ? attn_l : attn_r) + h * ND;
      float sums[8];
#pragma unroll
      for (int j = 0; j < 8; ++j) {
        const float4* wv = (const float4*)&W[(size_t)(k0 + j) * HD + h * ND];
        const float4* a4 = (const float4*)av;
        float sum = 0.f;
#pragma unroll
        for (int c4 = 0; c4 < ND / 4; ++c4) {
          const float4 w = wv[c4], a = a4[c4];
          sum += w.x * a.x + w.y * a.y + w.z * a.z + w.w * a.w;
        }
        sums[j] = sum;
      }
#pragma unroll
      for (int j2 = 0; j2 < 4; ++j2)
        pk[j2] = bf16b(sums[2 * j2]) | (bf16b(sums[2 * j2 + 1]) << 16);
    } else {
      pk[0] = pk[1] = pk[2] = pk[3] = 0;
    }
    *(uint4*)&wtx[r * 64 + ((s ^ (r & 7)) << 2)] =
        make_uint4(pk[0], pk[1], pk[2], pk[3]);
  }
  __shared__ int hist[1024];
  for (int b = t; b < nbuk; b += 256) hist[b] = 0;
  __syncthreads();
  const int chunk = (ne + NBLK - 1) / NBLK;
  const int start = blockIdx.x * chunk;
  const int end = min(start + chunk, ne);
  for (int e = start + t; e < end; e += 256)
    atomicAdd(&hist[dst[e] >> BSH], 1);
  __syncthreads();
  for (int b = t; b < nbuk; b += 256) cnt[b * NBLK + blockIdx.x] = hist[b];
}

// ---------------- Scan over the cnt table (generic length) -----------------
__global__ __launch_bounds__(256) void k_scan1(
    const int* __restrict__ in, int* __restrict__ pexcl,
    int* __restrict__ bsum, int len) {
  const int t = threadIdx.x;
  const int base = blockIdx.x * 1024 + t * 4;
  int v0 = base + 0 < len ? in[base + 0] : 0;
  int v1 = base + 1 < len ? in[base + 1] : 0;
  int v2 = base + 2 < len ? in[base + 2] : 0;
  int v3 = base + 3 < len ? in[base + 3] : 0;
  const int s = v0 + v1 + v2 + v3;
  const int lane = t & 63, w = t >> 6;
  int x = s;
#pragma unroll
  for (int off = 1; off < 64; off <<= 1) {
    int y = __shfl_up(x, off);
    if (lane >= off) x += y;
  }
  __shared__ int ws[4];
  if (lane == 63) ws[w] = x;
  __syncthreads();
  int woff = 0;
  for (int i = 0; i < w; ++i) woff += ws[i];
  int run = woff + x - s;
  if (base + 0 < len) { pexcl[base + 0] = run; run += v0; }
  if (base + 1 < len) { pexcl[base + 1] = run; run += v1; }
  if (base + 2 < len) { pexcl[base + 2] = run; run += v2; }
  if (base + 3 < len) { pexcl[base + 3] = run; run += v3; }
  if (t == 0) bsum[blockIdx.x] = ws[0] + ws[1] + ws[2] + ws[3];
}

__global__ __launch_bounds__(256) void k_scan23(
    const int* __restrict__ pexcl, const int* __restrict__ bsum,
    int* __restrict__ outv, int B, int len) {
  const int t = threadIdx.x;
  const int s = t < B ? bsum[t] : 0;
  const int lane = t & 63, w = t >> 6;
  int x = s;
#pragma unroll
  for (int off = 1; off < 64; off <<= 1) {
    int y = __shfl_up(x, off);
    if (lane >= off) x += y;
  }
  __shared__ int ws[4];
  __shared__ int sboff[256];
  if (lane == 63) ws[w] = x;
  __syncthreads();
  int woff = 0;
  for (int i = 0; i < w; ++i) woff += ws[i];
  sboff[t] = woff + x - s;
  __syncthreads();
  const int myoff = sboff[blockIdx.x];
  const int base = blockIdx.x * 1024 + t * 4;
#pragma unroll
  for (int j = 0; j < 4; ++j)
    if (base + j < len) outv[base + j] = pexcl[base + j] + myoff;
}

// ---- Kernel A: MFMA GEMM + fused coarse-partition tail --------------------
__global__ __launch_bounds__(256) void k_gemm(
    const float* __restrict__ feat, const unsigned* __restrict__ wtx,
    unsigned* __restrict__ ftb2, float* __restrict__ el, float* __restrict__ er,
    int n, const int* __restrict__ src, const int* __restrict__ dst,
    const int* __restrict__ scanned, unsigned* __restrict__ pairp,
    int ne, int nbuk) {
  __shared__ unsigned sB[144 * 64];  // 36864 B
  __shared__ int cur[1024];          // 4 KB (part tail)
  const int t = threadIdx.x;
  {
    const uint4* wx = (const uint4*)wtx;
    uint4* sx = (uint4*)sB;
    for (int it = t; it < 144 * 16; it += 256) sx[it] = wx[it];
  }
  __syncthreads();

  const int lane = t & 63;
  const int wv   = t >> 6;
  const int r0   = blockIdx.x * 128 + wv * 32;
  const int lrow = lane & 15;
  const int lk   = lane >> 4;

  if (r0 < n) {
    f32x4 acc[2][9];
#pragma unroll
    for (int st = 0; st < 2; ++st)
#pragma unroll
      for (int ct = 0; ct < 9; ++ct) acc[st][ct] = (f32x4)0.f;

#pragma unroll
    for (int ks = 0; ks < 4; ++ks) {
      short8 b[9];
#pragma unroll
      for (int ct = 0; ct < 9; ++ct) {
        const int row = ct * 16 + lrow;
        const int slot = ks * 4 + lk;
        b[ct] = *(const short8*)&sB[row * 64 + ((slot ^ (row & 7)) << 2)];
      }
#pragma unroll
      for (int st = 0; st < 2; ++st) {
        int arow = r0 + st * 16 + lrow;
        arow = arow < n ? arow : n - 1;
        const float* ap = feat + (size_t)arow * IN_F + ks * 32 + lk * 8;
        const float4 f0 = *(const float4*)ap;
        const float4 f1 = *(const float4*)(ap + 4);
        short8 a;
        a[0] = (short)bf16b(f0.x); a[1] = (short)bf16b(f0.y);
        a[2] = (short)bf16b(f0.z); a[3] = (short)bf16b(f0.w);
        a[4] = (short)bf16b(f1.x); a[5] = (short)bf16b(f1.y);
        a[6] = (short)bf16b(f1.z); a[7] = (short)bf16b(f1.w);
#pragma unroll
        for (int ct = 0; ct < 9; ++ct)
          acc[st][ct] = __builtin_amdgcn_mfma_f32_16x16x32_bf16(a, b[ct], acc[st][ct], 0, 0, 0);
      }
    }

#pragma unroll
    for (int st = 0; st < 2; ++st) {
#pragma unroll
      for (int i = 0; i < 4; ++i) {
        const int r = r0 + st * 16 + lk * 4 + i;
        if (r >= n) continue;
#pragma unroll
        for (int ct = 0; ct < 4; ++ct) {
          const unsigned pk = bf16b(acc[st][ct][i]) | (bf16b(acc[st][ct + 4][i]) << 16);
          ftb2[(size_t)r * 64 + ct * 16 + lrow] = pk;
        }
        if (lrow < 4)      el[r * NH + lrow]     = acc[st][8][i];
        else if (lrow < 8) er[r * NH + lrow - 4] = acc[st][8][i];
      }
    }
  }

  // ---- coarse-partition tail (blocks 0..NBLK-1 only; all waves alive) ----
  if (blockIdx.x < NBLK) {
    for (int b = t; b < nbuk; b += 256) cur[b] = scanned[b * NBLK + blockIdx.x];
    __syncthreads();
    const int chunk = (ne + NBLK - 1) / NBLK;
    const int start = blockIdx.x * chunk;
    const int end = min(start + chunk, ne);
    for (int e = start + t; e < end; e += 256) {
      const int d = dst[e];
      const int pos = atomicAdd(&cur[d >> BSH], 1);
      pairp[pos] = ((unsigned)src[e] << BSH) | (unsigned)(d & (BNODES - 1));
    }
  }
}

// ---- Kernel F: fused fine-sort + softmax + aggregation (one blk/bucket) ---
// Phase 1: LDS histogram+scan of the bucket's 128 nodes.
// Phase 2: build records (src, f16 p-pairs) in LDS (global spill if >CAP).
// Phase 3: aggregate — 16 lanes/node, 4 nodes/wave, 8 passes; records from
//          LDS, ftb2 gathered from global; one plain out-row store per node.
__global__ __launch_bounds__(256) void k_fsagg(
    const unsigned* __restrict__ pair, const int* __restrict__ scanned,
    const float* __restrict__ el, const float* __restrict__ er,
    const unsigned* __restrict__ ftb2, float* __restrict__ out,
    int4* __restrict__ spill, int n, int ne, int nbuk) {
  const int b = blockIdx.x;
  const int t = threadIdx.x;
  const int base = scanned[b * NBLK];
  const int endp = (b + 1 < nbuk) ? scanned[(b + 1) * NBLK] : ne;
  const bool spl = (endp - base) > CAP;  // block-uniform safety fallback
  __shared__ int hist[BNODES];
  __shared__ int cur[BNODES];
  __shared__ int ws2[2];
  __shared__ int s_src[CAP];
  __shared__ int2 s_h[CAP];

  // ---- phase 1: fine histogram + exclusive scan (local offsets) ----
  if (t < BNODES) hist[t] = 0;
  __syncthreads();
  for (int i = base + t; i < endp; i += 256)
    atomicAdd(&hist[pair[i] & (BNODES - 1)], 1);
  __syncthreads();
  int x = 0, v = 0;
  if (t < BNODES) {
    v = hist[t];
    x = v;
    const int lane = t & 63;
#pragma unroll
    for (int off = 1; off < 64; off <<= 1) {
      int y = __shfl_up(x, off);
      if (lane >= off) x += y;
    }
    if (lane == 63) ws2[t >> 6] = x;
  }
  __syncthreads();
  if (t < BNODES) {
    if (t >= 64) x += ws2[0];
    cur[t] = x - v;  // local exclusive offset
  }
  __syncthreads();

  // ---- phase 2: build records ----
  for (int i = base + t; i < endp; i += 256) {
    const unsigned pr = pair[i];
    const int s = (int)(pr >> BSH);
    const int fn = (int)(pr & (BNODES - 1));
    const int d = (b << BSH) + fn;
    const int pos = atomicAdd(&cur[fn], 1);
    const float4 l = *(const float4*)(el + (size_t)s * NH);
    const float4 r = *(const float4*)(er + (size_t)d * NH);
    float e0 = l.x + r.x, e1 = l.y + r.y, e2 = l.z + r.z, e3 = l.w + r.w;
    e0 = e0 > 0.f ? e0 : NEG_SLOPE * e0;
    e1 = e1 > 0.f ? e1 : NEG_SLOPE * e1;
    e2 = e2 > 0.f ? e2 : NEG_SLOPE * e2;
    e3 = e3 > 0.f ? e3 : NEG_SLOPE * e3;
    // |logits| <= ~8: exp() safe without segment-max; softmax ratio identical
    const __half2 h02 = __float22half2_rn(make_float2(__expf(e0), __expf(e2)));
    const __half2 h13 = __float22half2_rn(make_float2(__expf(e1), __expf(e3)));
    const int h02i = *(const int*)&h02;
    const int h13i = *(const int*)&h13;
    if (!spl) {
      s_src[pos] = s;
      s_h[pos] = make_int2(h02i, h13i);
    } else {
      spill[(size_t)base + pos] = make_int4(s, h02i, s, h13i);
    }
  }
  __syncthreads();

  // ---- phase 3: aggregate ----
  const int lane = t & 63;
  const int wv = t >> 6;
  const int q = lane >> 4;       // quarter 0..3
  const int c = lane & 15;       // lane within quarter
  const int hsel = c >> 3;       // 0:(p0,p2) 1:(p1,p3)
  const unsigned* fb = ftb2 + (c << 2);
  const int* sh = (const int*)s_h;

#define PKSTEP(SRCI, HV)                                              \
  {                                                                   \
    const uint4 vv = *(const uint4*)(fb + (size_t)(SRCI) * 64);       \
    const float2 pf = __half22float2(*(const __half2*)&(HV));         \
    f32x2 p; p.x = pf.x; p.y = pf.y;                                  \
    f32x2 f;                                                          \
    f.x = __uint_as_float(vv.x << 16);                                \
    f.y = __uint_as_float(vv.x & 0xFFFF0000u);                        \
    asm("v_pk_fma_f32 %0, %1, %2, %0" : "+v"(acc0) : "v"(f), "v"(p)); \
    f.x = __uint_as_float(vv.y << 16);                                \
    f.y = __uint_as_float(vv.y & 0xFFFF0000u);                        \
    asm("v_pk_fma_f32 %0, %1, %2, %0" : "+v"(acc1) : "v"(f), "v"(p)); \
    f.x = __uint_as_float(vv.z << 16);                                \
    f.y = __uint_as_float(vv.z & 0xFFFF0000u);                        \
    asm("v_pk_fma_f32 %0, %1, %2, %0" : "+v"(acc2) : "v"(f), "v"(p)); \
    f.x = __uint_as_float(vv.w << 16);                                \
    f.y = __uint_as_float(vv.w & 0xFFFF0000u);                        \
    asm("v_pk_fma_f32 %0, %1, %2, %0" : "+v"(acc3) : "v"(f), "v"(p)); \
    asm("v_pk_add_f32 %0, %1, %0" : "+v"(den) : "v"(p));              \
  }

  for (int pass = 0; pass < BNODES / 16; ++pass) {
    const int fn = pass * 16 + wv * 4 + q;
    const int node = (b << BSH) + fn;
    const int endl = cur[fn];
    const int startl = endl - hist[fn];
    f32x2 acc0 = {0.f, 0.f}, acc1 = {0.f, 0.f};
    f32x2 acc2 = {0.f, 0.f}, acc3 = {0.f, 0.f};
    f32x2 den  = {0.f, 0.f};

    if (!spl) {
      for (int i = startl; i < endl; i += 4) {
        int sidx[4], hv[4];
#pragma unroll
        for (int k = 0; k < 4; ++k) {
          const int idx = min(i + k, endl - 1);
          sidx[k] = s_src[idx];
          hv[k] = sh[idx * 2 + hsel];
          if (i + k >= endl) hv[k] = 0;
        }
#pragma unroll
        for (int k = 0; k < 4; ++k) PKSTEP(sidx[k], hv[k])
      }
    } else {
      const char* recb = (const char*)spill + (hsel << 3);
      const int gs = base + startl, ge = base + endl;
      for (int i = gs; i < ge; i += 4) {
        int2 r[4];
#pragma unroll
        for (int k = 0; k < 4; ++k) {
          const int idx = min(i + k, ge - 1);
          r[k] = *(const int2*)(recb + ((size_t)idx << 4));
          if (i + k >= ge) r[k].y = 0;
        }
#pragma unroll
        for (int k = 0; k < 4; ++k) PKSTEP(r[k].x, r[k].y)
      }
    }

    if (node < n) {
      const float d0 = den.x > 0.f ? den.x : 1.f;  // isolated-node guard
      const float d1 = den.y > 0.f ? den.y : 1.f;
      const float r0 = __builtin_amdgcn_rcpf(d0);
      const float r1 = __builtin_amdgcn_rcpf(d1);
      float* orow = out + (size_t)node * HD;
      *(float4*)(orow + (c << 2)) =
          make_float4(acc0.x * r0, acc1.x * r0, acc2.x * r0, acc3.x * r0);
      *(float4*)(orow + 64 + (c << 2)) =
          make_float4(acc0.y * r1, acc1.y * r1, acc2.y * r1, acc3.y * r1);
    }
  }
#undef PKSTEP
}

extern "C" void kernel_launch(void* const* d_in, const int* in_sizes, int n_in,
                              void* d_out, int out_size, void* d_ws, size_t ws_size,
                              hipStream_t stream) {
  const float* feat   = (const float*)d_in[0];
  const float* W      = (const float*)d_in[1];
  const float* attn_l = (const float*)d_in[2];
  const float* attn_r = (const float*)d_in[3];
  const int*   src    = (const int*)d_in[4];
  const int*   dst    = (const int*)d_in[5];
  const int n  = in_sizes[0] / IN_F;
  const int ne = in_sizes[4];
  float* out = (float*)d_out;

  const int nbuk = (n + BNODES - 1) >> BSH;   // coarse buckets (<=1024)
  const int tbl  = nbuk * NBLK;               // cnt table length
  const int Bt   = (tbl + 1023) / 1024;       // scan blocks (<=256)

  // workspace layout (16B-aligned blocks first)
  char* wp = (char*)d_ws;
  unsigned* ftb2  = (unsigned*)wp; wp += (size_t)n * 64 * 4;    // 25.6 MB
  int4*  spill    = (int4*)wp;     wp += (size_t)ne * 16;       // 25.6 MB
  unsigned* pairp = (unsigned*)wp; wp += (size_t)ne * 4;        // 6.4 MB
  unsigned* wtx   = (unsigned*)wp; wp += (size_t)144 * 64 * 4;  // 36 KB
  float* el       = (float*)wp;    wp += (size_t)n * NH * 4;
  float* er       = (float*)wp;    wp += (size_t)n * NH * 4;
  int*   cnt      = (int*)wp;      wp += (size_t)tbl * 4;
  int*   pexcl    = (int*)wp;      wp += (size_t)tbl * 4;
  int*   scanned  = (int*)wp;      wp += (size_t)tbl * 4;
  int*   bsum     = (int*)wp;      wp += 256 * 4;

  k_chist<<<NBLK, 256, 0, stream>>>(dst, cnt, ne, nbuk, W, attn_l, attn_r, wtx);
  k_scan1<<<Bt, 256, 0, stream>>>(cnt, pexcl, bsum, tbl);
  k_scan23<<<Bt, 256, 0, stream>>>(pexcl, bsum, scanned, Bt, tbl);
  k_gemm<<<(n + 127) / 128, 256, 0, stream>>>(feat, wtx, ftb2, el, er, n,
                                              src, dst, scanned, pairp, ne, nbuk);
  k_fsagg<<<nbuk, 256, 0, stream>>>(pairp, scanned, el, er, ftb2, out,
                                    spill, n, ne, nbuk);
}